// Round 3
// baseline (1038.675 us; speedup 1.0000x reference)
//
#include <hip/hip_runtime.h>

// B=32, T=1024, D=2048 fp32 scan along T.
// out[b,0,:] = x[b,0,:]
// t>=1: a=carry[j], bl=carry[j-1]; j==0: new = x+carry[0];
//       j>=1: p=sigmoid(a-bl); new = x + bl + p*(a-bl)
//
// R2 redesign: rocprof showed VGPR_Count=32 -> the 16-deep register prefetch
// pipeline never existed (spilled/sunk), each step exposed ~930 cyc of load
// latency. Fix: x staged through a 32-pair LDS ring via global_load_lds DMA
// (zero VGPR cost, compiler can't collapse it), counted s_waitcnt vmcnt(48)
// in-loop (never 0), one vmcnt(0) in the prologue only. ds_read prefetched
// 2 pairs ahead into registers. shfl_up replaced by DPP wave_shr:1 (~4 cyc
// vs ~120 for ds_bpermute on the serial chain). Boundary protocol unchanged
// (packed (t<<32|bits) slots, relaxed agent atomics, tag-match spin) but
// bbuf deepened to 16 so compiler-inserted waits for it (~vmcnt(48)) don't
// drain the DMA queue.

#define TT   1024
#define DD   2048
#define BLK  64
#define NCQ  16            // chunks (primary path)
#define VPT  2
#define CPC  (BLK*VPT)     // 128 cols per chunk
#define RP   32            // LDS ring depth in row-pairs (32 KiB)
#define NPAIR 512          // pair q = rows (2q+1, min(2q+2,1023))
#define DPB  16            // boundary slot prefetch depth (pow2)

typedef float v2f __attribute__((ext_vector_type(2)));

__device__ __forceinline__ float softstep(float a, float bl) {
    float d = a - bl;
    float p = __builtin_amdgcn_rcpf(1.0f + __expf(-d));
    return fmaf(p, d, bl);
}

// lane i gets lane i-1's value (lane 0 keeps own; overridden by select).
__device__ __forceinline__ float wave_shr1(float v) {
    int i = __builtin_amdgcn_update_dpp(__float_as_int(v), __float_as_int(v),
                                        0x138 /*wave_shr:1*/, 0xF, 0xF, false);
    return __int_as_float(i);
}

__global__ __launch_bounds__(BLK, 1)
void softscan_lds(const float* __restrict__ x, float* __restrict__ out,
                  unsigned long long* __restrict__ slots)
{
    const int b    = blockIdx.x;           // batch (XCD = b%8)
    const int k    = blockIdx.y;           // column chunk
    const int lane = threadIdx.x;
    const size_t xbase = (size_t)b * TT * DD;
    const int c0   = k * CPC + lane * VPT;          // compute cols
    const int colg = k * CPC + (lane & 31) * 4;     // DMA cols (16B/lane)

    v2f* op2 = (v2f*)(out + xbase + c0);

    unsigned long long* pubSlot =
        slots + ((size_t)b * (NCQ - 1) + k) * TT;          // valid if k < NCQ-1
    const unsigned long long* rdSlot =
        slots + ((size_t)b * (NCQ - 1) + (k - 1)) * TT;    // valid if k > 0

    __shared__ float ring[RP * 256];   // 32 slots x (2 rows x 128 floats)

    // t = 0
    v2f carry = *(const v2f*)(x + xbase + c0);
    __builtin_nontemporal_store(carry, &op2[0]);

    float xleft0 = 0.0f;
    if (k > 0 && lane == 0) xleft0 = x[xbase + c0 - 1];

    // DMA one row-pair q into ring slot q&31: lanes 0-31 row 2q+1, lanes
    // 32-63 row 2q+2 (clamped), 16B per lane, LDS dest = base + lane*16.
#define ISSUE_PAIR(Q_)                                                        \
    {                                                                         \
        const int q_ = (Q_);                                                  \
        int ra_ = 2 * q_ + 1 + (lane >> 5);                                   \
        if (ra_ > TT - 1) ra_ = TT - 1;                                       \
        const float* g_ = x + xbase + (size_t)ra_ * DD + colg;                \
        __builtin_amdgcn_global_load_lds(                                     \
            (const __attribute__((address_space(1))) void*)g_,                \
            (__attribute__((address_space(3))) void*)&ring[(q_ & (RP-1))*256],\
            16, 0, 0);                                                        \
    }

#define READ_PAIR(Q_, A_, B_)                                                 \
    {                                                                         \
        const float* lb_ = &ring[((Q_) & (RP - 1)) * 256 + lane * 2];         \
        A_ = *(const v2f*)lb_;                                                \
        B_ = *(const v2f*)(lb_ + 128);                                        \
    }

    unsigned long long bbuf[DPB];   // compile-time indexed only (rule #20)

    // prologue: fill the DMA ring + boundary prefetch, then one full drain.
#pragma unroll
    for (int q = 0; q < RP; ++q) ISSUE_PAIR(q)
    if (k > 0 && lane == 0) {
#pragma unroll
        for (int s = 1; s < DPB; ++s)
            bbuf[s] = __hip_atomic_load(&rdSlot[s], __ATOMIC_RELAXED,
                                        __HIP_MEMORY_SCOPE_AGENT);
    }
    asm volatile("s_waitcnt vmcnt(0)" ::: "memory");

    v2f xc0, xc1, xn0, xn1;
    READ_PAIR(0, xc0, xc1)
    READ_PAIR(1, xn0, xn1)

    // JS_ must be a compile-time constant (bbuf stays in registers).
#define DOSTEP(S_, JS_, XV_)                                                  \
    {                                                                         \
        const int s_ = (S_);                                                  \
        const int t_ = s_ + 1;                                                \
        float leftv_ = 0.0f;                                                  \
        if (k > 0 && lane == 0) {                                             \
            if (s_ == 0) leftv_ = xleft0;                                     \
            else {                                                            \
                unsigned long long raw_ = bbuf[(JS_)];                        \
                while ((unsigned)(raw_ >> 32) != (unsigned)s_)                \
                    raw_ = __hip_atomic_load(&rdSlot[s_], __ATOMIC_RELAXED,   \
                                             __HIP_MEMORY_SCOPE_AGENT);       \
                leftv_ = __uint_as_float((unsigned)raw_);                     \
            }                                                                 \
        }                                                                     \
        float sh_   = wave_shr1(carry.y);                                     \
        float left_ = (lane == 0) ? leftv_ : sh_;                             \
        float n0_ = (XV_).x + ((k == 0 && lane == 0)                          \
                                   ? carry.x : softstep(carry.x, left_));     \
        float n1_ = (XV_).y + softstep(carry.y, carry.x);                     \
        carry.x = n0_; carry.y = n1_;                                         \
        __builtin_nontemporal_store(carry, &op2[(size_t)t_ * (DD / VPT)]);    \
        if (k < NCQ - 1 && lane == BLK - 1 && t_ <= TT - 2) {                 \
            unsigned long long pk_ =                                          \
                ((unsigned long long)(unsigned)t_ << 32) |                    \
                (unsigned long long)__float_as_uint(n1_);                     \
            __hip_atomic_store(&pubSlot[t_], pk_, __ATOMIC_RELAXED,           \
                               __HIP_MEMORY_SCOPE_AGENT);                     \
        }                                                                     \
        const int spb_ = s_ + DPB;                                            \
        if (k > 0 && lane == 0 && spb_ <= TT - 2)                             \
            bbuf[(JS_)] = __hip_atomic_load(&rdSlot[spb_], __ATOMIC_RELAXED,  \
                                            __HIP_MEMORY_SCOPE_AGENT);        \
    }

    // main: 63 groups x 8 pairs (p = 0..503); s&15 == 2j so bbuf indices fold
    int p = 0;
    for (int m = 0; m < 63; ++m) {
#pragma unroll
        for (int j = 0; j < 8; ++j) {
            const int s0 = 2 * p;                  // = 16m + 2j
            DOSTEP(s0,     2 * j,     xc0)
            DOSTEP(s0 + 1, 2 * j + 1, xc1)
            if (p + RP < NPAIR) ISSUE_PAIR(p + RP)
            // counted wait: pair p+2's DMA has >=120 vmem ops after it
            // (or was prologue-covered by the vmcnt(0)); 48 never drains
            // the young loads -> pipeline stays full.
            asm volatile("s_waitcnt vmcnt(48)" ::: "memory");
            int pr = p + 2; if (pr > NPAIR - 1) pr = NPAIR - 1;
            v2f a0, a1; READ_PAIR(pr, a0, a1)
            xc0 = xn0; xc1 = xn1; xn0 = a0; xn1 = a1;
            ++p;
        }
    }
    // tail pairs p = 504..510 (rows 1009..1022); (1008+2e)&15 == 2e
#pragma unroll
    for (int e = 0; e < 7; ++e) {
        const int s0 = 2 * (504 + e);
        DOSTEP(s0,     2 * e,     xc0)
        DOSTEP(s0 + 1, 2 * e + 1, xc1)
        asm volatile("s_waitcnt vmcnt(48)" ::: "memory");
        int pr = 504 + e + 2; if (pr > NPAIR - 1) pr = NPAIR - 1;
        v2f a0, a1; READ_PAIR(pr, a0, a1)
        xc0 = xn0; xc1 = xn1; xn0 = a0; xn1 = a1;
    }
    // final row t = 1023 (s = 1022, 1022&15 == 14)
    DOSTEP(1022, 14, xc0)

#undef DOSTEP
#undef READ_PAIR
#undef ISSUE_PAIR
}

// ---- legacy register-pipeline kernel: NC=8 fallback (small workspace) ----
#define DPX 16

__device__ __forceinline__ float softstep_legacy(float a, float bl) {
    return softstep(a, bl);
}

template<int NC>
__global__ __launch_bounds__(BLK, 1)
void softscan_kernel(const float* __restrict__ x, float* __restrict__ out,
                     unsigned long long* __restrict__ slots)
{
    constexpr int VPTL = DD / NC / BLK;
    typedef float vecN __attribute__((ext_vector_type(VPTL)));

    const int b    = blockIdx.x;
    const int k    = blockIdx.y;
    const int lane = threadIdx.x;
    const int c0   = k * (BLK * VPTL) + lane * VPTL;
    const int strideV = DD / VPTL;

    const vecN* __restrict__ xp = (const vecN*)(x + (size_t)b * TT * DD + c0);
    vecN* __restrict__ op       = (vecN*)(out + (size_t)b * TT * DD + c0);

    unsigned long long* pubSlot =
        slots + ((size_t)b * (NC - 1) + k) * TT;
    const unsigned long long* rdSlot =
        slots + ((size_t)b * (NC - 1) + (k - 1)) * TT;

    vecN carry = xp[0];
    __builtin_nontemporal_store(carry, &op[0]);

    float xleft0 = 0.0f;
    if (k > 0 && lane == 0) xleft0 = x[(size_t)b * TT * DD + (c0 - 1)];

    vecN xbuf[DPX];
    unsigned long long bbuf[8];
#pragma unroll
    for (int s = 0; s < DPX; ++s)
        xbuf[s] = xp[(size_t)(s + 1) * strideV];
    if (k > 0 && lane == 0) {
#pragma unroll
        for (int s = 1; s < 8; ++s)
            bbuf[s] = __hip_atomic_load(&rdSlot[s], __ATOMIC_RELAXED,
                                        __HIP_MEMORY_SCOPE_AGENT);
    }

#define STEP_BODY(S_, J_, PF_X_)                                              \
    {                                                                         \
        const int s = (S_);                                                   \
        const int t = s + 1;                                                  \
        vecN xv = xbuf[(J_)];                                                 \
        float leftv = 0.0f;                                                   \
        if (k > 0 && lane == 0) {                                             \
            if (s == 0) leftv = xleft0;                                       \
            else {                                                            \
                unsigned long long raw = bbuf[(J_) & 7];                      \
                while ((unsigned)(raw >> 32) != (unsigned)s)                  \
                    raw = __hip_atomic_load(&rdSlot[s], __ATOMIC_RELAXED,     \
                                            __HIP_MEMORY_SCOPE_AGENT);        \
                leftv = __uint_as_float((unsigned)raw);                       \
            }                                                                 \
        }                                                                     \
        float sh   = __shfl_up(carry[VPTL - 1], 1);                           \
        float left = (lane == 0) ? leftv : sh;                                \
        vecN n;                                                               \
        float s0 = softstep(carry[0], left);                                  \
        n[0] = xv[0] + ((k == 0 && lane == 0) ? carry[0] : s0);               \
        _Pragma("unroll")                                                     \
        for (int i = 1; i < VPTL; ++i)                                        \
            n[i] = xv[i] + softstep(carry[i], carry[i - 1]);                  \
        carry = n;                                                            \
        __builtin_nontemporal_store(carry, &op[(size_t)t * strideV]);         \
        if (k < NC - 1 && lane == BLK - 1 && t <= TT - 2) {                   \
            unsigned long long pk =                                           \
                ((unsigned long long)(unsigned)t << 32) |                     \
                (unsigned long long)__float_as_uint(carry[VPTL - 1]);         \
            __hip_atomic_store(&pubSlot[t], pk, __ATOMIC_RELAXED,             \
                               __HIP_MEMORY_SCOPE_AGENT);                     \
        }                                                                     \
        if (PF_X_) {                                                          \
            int row = s + DPX + 1; if (row > TT - 1) row = TT - 1;            \
            xbuf[(J_)] = xp[(size_t)row * strideV];                           \
        }                                                                     \
        const int spb = s + 8;                                                \
        if (k > 0 && lane == 0 && spb <= TT - 2)                              \
            bbuf[(J_) & 7] =                                                  \
                __hip_atomic_load(&rdSlot[spb], __ATOMIC_RELAXED,             \
                                  __HIP_MEMORY_SCOPE_AGENT);                  \
    }

    for (int m = 0; m < (TT - 1) / DPX; ++m) {
#pragma unroll
        for (int j = 0; j < DPX; ++j)
            STEP_BODY(m * DPX + j, j, true)
    }
#pragma unroll
    for (int e = 0; e < (TT - 1) % DPX; ++e)
        STEP_BODY(((TT - 1) / DPX) * DPX + e, e, false)

#undef STEP_BODY
}

// Workspace-free correctness fallback: one wave per batch owns all of D.
__global__ __launch_bounds__(BLK, 1)
void softscan_fallback(const float* __restrict__ x, float* __restrict__ out)
{
    constexpr int VPTF = DD / BLK;  // 32
    const int b    = blockIdx.x;
    const int lane = threadIdx.x;
    const int c0   = lane * VPTF;

    const float* __restrict__ xp = x + (size_t)b * TT * DD + c0;
    float* __restrict__ op       = out + (size_t)b * TT * DD + c0;

    float carry[VPTF];
#pragma unroll
    for (int i = 0; i < VPTF; ++i) carry[i] = xp[i];
#pragma unroll
    for (int i = 0; i < VPTF; ++i) op[i] = carry[i];

    for (int t = 1; t < TT; ++t) {
        const float* xr = xp + (size_t)t * DD;
        float* orow     = op + (size_t)t * DD;
        float xv[VPTF];
#pragma unroll
        for (int i = 0; i < VPTF; ++i) xv[i] = xr[i];

        float sh = __shfl_up(carry[VPTF - 1], 1);
        float n[VPTF];
        if (lane == 0) n[0] = xv[0] + carry[0];
        else           n[0] = xv[0] + softstep(carry[0], sh);
#pragma unroll
        for (int i = 1; i < VPTF; ++i)
            n[i] = xv[i] + softstep(carry[i], carry[i - 1]);
#pragma unroll
        for (int i = 0; i < VPTF; ++i) { carry[i] = n[i]; orow[i] = n[i]; }
    }
}

extern "C" void kernel_launch(void* const* d_in, const int* in_sizes, int n_in,
                              void* d_out, int out_size, void* d_ws, size_t ws_size,
                              hipStream_t stream) {
    const float* x = (const float*)d_in[0];
    float* out = (float*)d_out;
    unsigned long long* slots = (unsigned long long*)d_ws;
    const size_t need16 = (size_t)32 * 15 * TT * sizeof(unsigned long long); // 3.75 MB
    const size_t need8  = (size_t)32 * 7  * TT * sizeof(unsigned long long); // 1.75 MB
    if (d_ws != nullptr && ws_size >= need16) {
        softscan_lds<<<dim3(32, NCQ), dim3(BLK), 0, stream>>>(x, out, slots);
    } else if (d_ws != nullptr && ws_size >= need8) {
        softscan_kernel<8><<<dim3(32, 8), dim3(BLK), 0, stream>>>(x, out, slots);
    } else {
        softscan_fallback<<<dim3(32), dim3(BLK), 0, stream>>>(x, out);
    }
}

// Round 4
// 681.225 us; speedup vs baseline: 1.5247x; 1.5247x over previous
//
#include <hip/hip_runtime.h>

// B=32, T=1024, D=2048 fp32 scan along T.
// out[b,0,:] = x[b,0,:]
// t>=1: a=carry[j], bl=carry[j-1]; j==0: new = x+carry[0];
//       j>=1: p=sigmoid(a-bl); new = x + bl + p*(a-bl)
//
// R4: revert LDS-DMA ring (R3 regressed 398->745: compiler serialized
// ds_read vs in-flight global_load_lds, ~full DMA latency per iter).
// Root cause of the 398 baseline found in its counters: VGPR_Count=32 ->
// xbuf[16] (32 VGPRs min) was NEVER in registers; the unroller gave up on
// the body containing the spin-while, indices went runtime, array demoted
// to scratch (rule #20) -> ~930 cyc scratch round-trip at use per step.
// Fix: 16-deep x pipeline + 8-deep boundary pipeline as NAMED registers
// (X0..X15, B0..B7), 16-step body macro-expanded -> nothing to demote.
// Loads issue 16 steps before use; compiler inserts counted at-use waits.
// DPP wave_shr:1 (validated R3) replaces ds_bpermute on the serial chain.
// No inline-asm waitcnts. No LDS.
// Boundary protocol unchanged: packed (t<<32|bits) slots in d_ws, relaxed
// agent-scope atomics, tag-match spin. Grid (b,k): linear id = b + 32k ->
// XCD = b%8, all chunks of a batch share an XCD's L2.

#define TT   1024
#define DD   2048
#define BLK  64
#define NCQ  16            // chunks (primary path)
#define VPT  2
#define DPX  16            // x prefetch depth (named regs)
#define DPB  8             // boundary prefetch depth (named regs)

typedef float v2f __attribute__((ext_vector_type(2)));

__device__ __forceinline__ float softstep(float a, float bl) {
    float d = a - bl;
    float p = __builtin_amdgcn_rcpf(1.0f + __expf(-d));
    return fmaf(p, d, bl);
}

// lane i gets lane i-1's value (lane 0 keeps own; overridden by select).
__device__ __forceinline__ float wave_shr1(float v) {
    int i = __builtin_amdgcn_update_dpp(__float_as_int(v), __float_as_int(v),
                                        0x138 /*wave_shr:1*/, 0xF, 0xF, false);
    return __int_as_float(i);
}

__global__ __launch_bounds__(BLK, 1)
void softscan_regs(const float* __restrict__ x, float* __restrict__ out,
                   unsigned long long* __restrict__ slots)
{
    const int b    = blockIdx.x;           // batch (XCD = b%8)
    const int k    = blockIdx.y;           // column chunk
    const int lane = threadIdx.x;
    const size_t xbase = (size_t)b * TT * DD;
    const int c0   = k * (BLK * VPT) + lane * VPT;

    const float* __restrict__ xrow = x + xbase + c0;    // + t*DD per row
    v2f* __restrict__ op2 = (v2f*)(out + xbase + c0);

    unsigned long long* pubSlot =
        slots + ((size_t)b * (NCQ - 1) + k) * TT;          // valid if k < NCQ-1
    const unsigned long long* rdSlot =
        slots + ((size_t)b * (NCQ - 1) + (k - 1)) * TT;    // valid if k > 0

    // t = 0
    v2f carry = *(const v2f*)xrow;
    __builtin_nontemporal_store(carry, &op2[0]);

    float xleft0 = 0.0f;
    if (k > 0 && lane == 0) xleft0 = x[xbase + c0 - 1];

    // ---- named-register pipelines ----
    v2f X0, X1, X2, X3, X4, X5, X6, X7, X8, X9, X10, X11, X12, X13, X14, X15;
    unsigned long long B0 = 0, B1 = 0, B2 = 0, B3 = 0,
                       B4 = 0, B5 = 0, B6 = 0, B7 = 0;

    // prologue: X_i = row i+1 (rows 1..16); B_j = rdSlot[j] (tags 1..7)
#define PLX(I_) X##I_ = *(const v2f*)(xrow + (size_t)(((I_) + 1) * DD));
    PLX(0) PLX(1) PLX(2) PLX(3) PLX(4) PLX(5) PLX(6) PLX(7)
    PLX(8) PLX(9) PLX(10) PLX(11) PLX(12) PLX(13) PLX(14) PLX(15)
#undef PLX
    if (k > 0 && lane == 0) {
        B1 = __hip_atomic_load(&rdSlot[1], __ATOMIC_RELAXED, __HIP_MEMORY_SCOPE_AGENT);
        B2 = __hip_atomic_load(&rdSlot[2], __ATOMIC_RELAXED, __HIP_MEMORY_SCOPE_AGENT);
        B3 = __hip_atomic_load(&rdSlot[3], __ATOMIC_RELAXED, __HIP_MEMORY_SCOPE_AGENT);
        B4 = __hip_atomic_load(&rdSlot[4], __ATOMIC_RELAXED, __HIP_MEMORY_SCOPE_AGENT);
        B5 = __hip_atomic_load(&rdSlot[5], __ATOMIC_RELAXED, __HIP_MEMORY_SCOPE_AGENT);
        B6 = __hip_atomic_load(&rdSlot[6], __ATOMIC_RELAXED, __HIP_MEMORY_SCOPE_AGENT);
        B7 = __hip_atomic_load(&rdSlot[7], __ATOMIC_RELAXED, __HIP_MEMORY_SCOPE_AGENT);
    }

    // step s: consumes X (row s+1) and B (slot tag s, if s%8 matches);
    // reloads X = row s+17 (clamped), B = rdSlot[s+8].
#define STEP(S_, XV_, BV_, PFX_)                                              \
    {                                                                         \
        const int s_ = (S_);                                                  \
        const int t_ = s_ + 1;                                                \
        float leftv_ = 0.0f;                                                  \
        if (k > 0 && lane == 0) {                                             \
            if (s_ == 0) leftv_ = xleft0;                                     \
            else {                                                            \
                unsigned long long raw_ = (BV_);                              \
                while ((unsigned)(raw_ >> 32) != (unsigned)s_)                \
                    raw_ = __hip_atomic_load(&rdSlot[s_], __ATOMIC_RELAXED,   \
                                             __HIP_MEMORY_SCOPE_AGENT);       \
                leftv_ = __uint_as_float((unsigned)raw_);                     \
            }                                                                 \
        }                                                                     \
        float sh_   = wave_shr1(carry.y);                                     \
        float left_ = (lane == 0) ? leftv_ : sh_;                             \
        float n0_ = (XV_).x + ((k == 0 && lane == 0)                          \
                                   ? carry.x : softstep(carry.x, left_));     \
        float n1_ = (XV_).y + softstep(carry.y, carry.x);                     \
        carry.x = n0_; carry.y = n1_;                                         \
        __builtin_nontemporal_store(carry, &op2[(size_t)t_ * (DD / VPT)]);    \
        if (k < NCQ - 1 && lane == BLK - 1 && t_ <= TT - 2) {                 \
            unsigned long long pk_ =                                          \
                ((unsigned long long)(unsigned)t_ << 32) |                    \
                (unsigned long long)__float_as_uint(n1_);                     \
            __hip_atomic_store(&pubSlot[t_], pk_, __ATOMIC_RELAXED,           \
                               __HIP_MEMORY_SCOPE_AGENT);                     \
        }                                                                     \
        if (PFX_) {                                                           \
            int pr_ = s_ + DPX + 1; if (pr_ > TT - 1) pr_ = TT - 1;           \
            (XV_) = *(const v2f*)(xrow + (size_t)(pr_ * DD));                 \
        }                                                                     \
        const int spb_ = s_ + DPB;                                            \
        if (k > 0 && lane == 0 && spb_ <= TT - 2)                             \
            (BV_) = __hip_atomic_load(&rdSlot[spb_], __ATOMIC_RELAXED,        \
                                      __HIP_MEMORY_SCOPE_AGENT);              \
    }

    // main: 63 blocks of 16 explicit steps, s = 0..1007
    for (int m = 0; m < (TT - 1) / DPX; ++m) {
        const int s0 = m * DPX;
        STEP(s0 +  0, X0,  B0, true)
        STEP(s0 +  1, X1,  B1, true)
        STEP(s0 +  2, X2,  B2, true)
        STEP(s0 +  3, X3,  B3, true)
        STEP(s0 +  4, X4,  B4, true)
        STEP(s0 +  5, X5,  B5, true)
        STEP(s0 +  6, X6,  B6, true)
        STEP(s0 +  7, X7,  B7, true)
        STEP(s0 +  8, X8,  B0, true)
        STEP(s0 +  9, X9,  B1, true)
        STEP(s0 + 10, X10, B2, true)
        STEP(s0 + 11, X11, B3, true)
        STEP(s0 + 12, X12, B4, true)
        STEP(s0 + 13, X13, B5, true)
        STEP(s0 + 14, X14, B6, true)
        STEP(s0 + 15, X15, B7, true)
    }
    // tail: 15 steps, s = 1008..1022 (X0..X14 hold rows 1009..1023)
    {
        const int s0 = ((TT - 1) / DPX) * DPX;   // 1008
        STEP(s0 +  0, X0,  B0, false)
        STEP(s0 +  1, X1,  B1, false)
        STEP(s0 +  2, X2,  B2, false)
        STEP(s0 +  3, X3,  B3, false)
        STEP(s0 +  4, X4,  B4, false)
        STEP(s0 +  5, X5,  B5, false)
        STEP(s0 +  6, X6,  B6, false)
        STEP(s0 +  7, X7,  B7, false)
        STEP(s0 +  8, X8,  B0, false)
        STEP(s0 +  9, X9,  B1, false)
        STEP(s0 + 10, X10, B2, false)
        STEP(s0 + 11, X11, B3, false)
        STEP(s0 + 12, X12, B4, false)
        STEP(s0 + 13, X13, B5, false)
        STEP(s0 + 14, X14, B6, false)
    }
#undef STEP
}

// ---- legacy NC=8 fallback (small workspace) ----
#define DPXL 16

template<int NC>
__global__ __launch_bounds__(BLK, 1)
void softscan_kernel(const float* __restrict__ x, float* __restrict__ out,
                     unsigned long long* __restrict__ slots)
{
    constexpr int VPTL = DD / NC / BLK;
    typedef float vecN __attribute__((ext_vector_type(VPTL)));

    const int b    = blockIdx.x;
    const int k    = blockIdx.y;
    const int lane = threadIdx.x;
    const int c0   = k * (BLK * VPTL) + lane * VPTL;
    const int strideV = DD / VPTL;

    const vecN* __restrict__ xp = (const vecN*)(x + (size_t)b * TT * DD + c0);
    vecN* __restrict__ op       = (vecN*)(out + (size_t)b * TT * DD + c0);

    unsigned long long* pubSlot =
        slots + ((size_t)b * (NC - 1) + k) * TT;
    const unsigned long long* rdSlot =
        slots + ((size_t)b * (NC - 1) + (k - 1)) * TT;

    vecN carry = xp[0];
    __builtin_nontemporal_store(carry, &op[0]);

    float xleft0 = 0.0f;
    if (k > 0 && lane == 0) xleft0 = x[(size_t)b * TT * DD + (c0 - 1)];

    vecN xbuf[DPXL];
    unsigned long long bbuf[8];
#pragma unroll
    for (int s = 0; s < DPXL; ++s)
        xbuf[s] = xp[(size_t)(s + 1) * strideV];
    if (k > 0 && lane == 0) {
#pragma unroll
        for (int s = 1; s < 8; ++s)
            bbuf[s] = __hip_atomic_load(&rdSlot[s], __ATOMIC_RELAXED,
                                        __HIP_MEMORY_SCOPE_AGENT);
    }

#define STEP_BODY(S_, J_, PF_X_)                                              \
    {                                                                         \
        const int s = (S_);                                                   \
        const int t = s + 1;                                                  \
        vecN xv = xbuf[(J_)];                                                 \
        float leftv = 0.0f;                                                   \
        if (k > 0 && lane == 0) {                                             \
            if (s == 0) leftv = xleft0;                                       \
            else {                                                            \
                unsigned long long raw = bbuf[(J_) & 7];                      \
                while ((unsigned)(raw >> 32) != (unsigned)s)                  \
                    raw = __hip_atomic_load(&rdSlot[s], __ATOMIC_RELAXED,     \
                                            __HIP_MEMORY_SCOPE_AGENT);        \
                leftv = __uint_as_float((unsigned)raw);                       \
            }                                                                 \
        }                                                                     \
        float sh   = __shfl_up(carry[VPTL - 1], 1);                           \
        float left = (lane == 0) ? leftv : sh;                                \
        vecN n;                                                               \
        float s0v = softstep(carry[0], left);                                 \
        n[0] = xv[0] + ((k == 0 && lane == 0) ? carry[0] : s0v);              \
        _Pragma("unroll")                                                     \
        for (int i = 1; i < VPTL; ++i)                                        \
            n[i] = xv[i] + softstep(carry[i], carry[i - 1]);                  \
        carry = n;                                                            \
        __builtin_nontemporal_store(carry, &op[(size_t)t * strideV]);         \
        if (k < NC - 1 && lane == BLK - 1 && t <= TT - 2) {                   \
            unsigned long long pk =                                           \
                ((unsigned long long)(unsigned)t << 32) |                     \
                (unsigned long long)__float_as_uint(carry[VPTL - 1]);         \
            __hip_atomic_store(&pubSlot[t], pk, __ATOMIC_RELAXED,             \
                               __HIP_MEMORY_SCOPE_AGENT);                     \
        }                                                                     \
        if (PF_X_) {                                                          \
            int row = s + DPXL + 1; if (row > TT - 1) row = TT - 1;           \
            xbuf[(J_)] = xp[(size_t)row * strideV];                           \
        }                                                                     \
        const int spb = s + 8;                                                \
        if (k > 0 && lane == 0 && spb <= TT - 2)                              \
            bbuf[(J_) & 7] =                                                  \
                __hip_atomic_load(&rdSlot[spb], __ATOMIC_RELAXED,             \
                                  __HIP_MEMORY_SCOPE_AGENT);                  \
    }

    for (int m = 0; m < (TT - 1) / DPXL; ++m) {
#pragma unroll
        for (int j = 0; j < DPXL; ++j)
            STEP_BODY(m * DPXL + j, j, true)
    }
#pragma unroll
    for (int e = 0; e < (TT - 1) % DPXL; ++e)
        STEP_BODY(((TT - 1) / DPXL) * DPXL + e, e, false)

#undef STEP_BODY
}

// Workspace-free correctness fallback: one wave per batch owns all of D.
__global__ __launch_bounds__(BLK, 1)
void softscan_fallback(const float* __restrict__ x, float* __restrict__ out)
{
    constexpr int VPTF = DD / BLK;  // 32
    const int b    = blockIdx.x;
    const int lane = threadIdx.x;
    const int c0   = lane * VPTF;

    const float* __restrict__ xp = x + (size_t)b * TT * DD + c0;
    float* __restrict__ op       = out + (size_t)b * TT * DD + c0;

    float carry[VPTF];
#pragma unroll
    for (int i = 0; i < VPTF; ++i) carry[i] = xp[i];
#pragma unroll
    for (int i = 0; i < VPTF; ++i) op[i] = carry[i];

    for (int t = 1; t < TT; ++t) {
        const float* xr = xp + (size_t)t * DD;
        float* orow     = op + (size_t)t * DD;
        float xv[VPTF];
#pragma unroll
        for (int i = 0; i < VPTF; ++i) xv[i] = xr[i];

        float sh = __shfl_up(carry[VPTF - 1], 1);
        float n[VPTF];
        if (lane == 0) n[0] = xv[0] + carry[0];
        else           n[0] = xv[0] + softstep(carry[0], sh);
#pragma unroll
        for (int i = 1; i < VPTF; ++i)
            n[i] = xv[i] + softstep(carry[i], carry[i - 1]);
#pragma unroll
        for (int i = 0; i < VPTF; ++i) { carry[i] = n[i]; orow[i] = n[i]; }
    }
}

extern "C" void kernel_launch(void* const* d_in, const int* in_sizes, int n_in,
                              void* d_out, int out_size, void* d_ws, size_t ws_size,
                              hipStream_t stream) {
    const float* x = (const float*)d_in[0];
    float* out = (float*)d_out;
    unsigned long long* slots = (unsigned long long*)d_ws;
    const size_t need16 = (size_t)32 * 15 * TT * sizeof(unsigned long long); // 3.75 MB
    const size_t need8  = (size_t)32 * 7  * TT * sizeof(unsigned long long); // 1.75 MB
    if (d_ws != nullptr && ws_size >= need16) {
        softscan_regs<<<dim3(32, NCQ), dim3(BLK), 0, stream>>>(x, out, slots);
    } else if (d_ws != nullptr && ws_size >= need8) {
        softscan_kernel<8><<<dim3(32, 8), dim3(BLK), 0, stream>>>(x, out, slots);
    } else {
        softscan_fallback<<<dim3(32), dim3(BLK), 0, stream>>>(x, out);
    }
}